// Round 1
// baseline (107.810 us; speedup 1.0000x reference)
//
#include <hip/hip_runtime.h>
#include <math.h>

// RoPE: x (8,16,4096,128) fp32, interleaved even/odd pairing.
// out[..., 2k]   = cos(ang_k)*x[...,2k] - sin(ang_k)*x[...,2k+1]
// out[..., 2k+1] = sin(ang_k)*x[...,2k] + cos(ang_k)*x[...,2k+1]
// ang_k = pos * 10000^(-2k/128)
//
// Memory-bound (512 MiB traffic). Strategy: one thread owns one
// (s, float4-chunk) angle pair and loops over 16 of the 128 bh-slices,
// so the sincos cost is amortized 16x and the hot loop is pure
// float4 load -> 8 FMA -> float4 store, fully coalesced.

#define S_LEN   4096
#define D_HEAD  128
#define CHUNKS  32          // float4 chunks per d-row (128/4)
#define BH      128         // 8*16 batch*heads
#define BH_PER_THREAD 16
#define GROUPS  (BH / BH_PER_THREAD)   // 8

__global__ __launch_bounds__(256)
void rope_kernel(const float* __restrict__ x,
                 const int*   __restrict__ pos,
                 float*       __restrict__ out) {
    const int tid = blockIdx.x * 256 + threadIdx.x;     // 0 .. 8*131072-1
    const int idx = tid & (S_LEN * CHUNKS - 1);          // 0 .. 131071 (2^17-1)
    const int g   = tid >> 17;                           // bh group 0..7

    const int s = idx >> 5;          // sequence position 0..4095
    const int c = idx & 31;          // float4 chunk in row -> pairs k=2c, 2c+1

    const float p = (float)pos[s];

    // inv_freq[k] = 10000^(-2k/128) = exp(k * (-2/128)*ln(10000))
    const float lg = (-2.0f / 128.0f) * logf(10000.0f);
    const float f0 = __expf(lg * (float)(2 * c));
    const float f1 = __expf(lg * (float)(2 * c + 1));

    float s0, c0, s1, c1;
    sincosf(p * f0, &s0, &c0);
    sincosf(p * f1, &s1, &c1);

    const size_t stride = (size_t)S_LEN * D_HEAD;        // one bh-slice
    size_t base = (size_t)(g * BH_PER_THREAD) * stride
                + (size_t)s * D_HEAD + (size_t)(c * 4);

    #pragma unroll 4
    for (int i = 0; i < BH_PER_THREAD; ++i) {
        const float4 v = *reinterpret_cast<const float4*>(x + base);
        float4 o;
        o.x = c0 * v.x - s0 * v.y;
        o.y = s0 * v.x + c0 * v.y;
        o.z = c1 * v.z - s1 * v.w;
        o.w = s1 * v.z + c1 * v.w;
        *reinterpret_cast<float4*>(out + base) = o;
        base += stride;
    }
}

extern "C" void kernel_launch(void* const* d_in, const int* in_sizes, int n_in,
                              void* d_out, int out_size, void* d_ws, size_t ws_size,
                              hipStream_t stream) {
    const float* x   = (const float*)d_in[0];
    const int*   pos = (const int*)d_in[1];
    float*       out = (float*)d_out;

    // total threads = GROUPS * S_LEN * CHUNKS = 8 * 131072 = 1,048,576
    const int total  = GROUPS * S_LEN * CHUNKS;
    const int blocks = total / 256;   // 4096
    rope_kernel<<<blocks, 256, 0, stream>>>(x, pos, out);
}

// Round 3
// 92.073 us; speedup vs baseline: 1.1709x; 1.1709x over previous
//
#include <hip/hip_runtime.h>
#include <math.h>

// RoPE: x (8,16,4096,128) fp32, interleaved even/odd pairing.
// out[..., 2k]   = cos(ang_k)*x[...,2k] - sin(ang_k)*x[...,2k+1]
// out[..., 2k+1] = sin(ang_k)*x[...,2k] + cos(ang_k)*x[...,2k+1]
// ang_k = pos * 10000^(-2k/128)
//
// Memory-bound streaming kernel (537 MB traffic, zero reuse, working set
// 2x the 256 MiB L3). Strategy:
//  - one thread owns one (s, float4-chunk) angle pair -> sincos amortized
//    over 16 bh-slices; hot loop is NT-load -> 8 FMA -> NT-store.
//  - nontemporal load/store (clang ext_vector, NOT HIP float4 — the
//    builtin rejects the struct wrapper): no cache allocation for either
//    stream, avoiding pure L3/L2 thrash.
//  - unroll 8: 8 loads in flight per wave for latency hiding.

typedef float f32x4 __attribute__((ext_vector_type(4)));

#define S_LEN   4096
#define D_HEAD  128
#define CHUNKS  32          // float4 chunks per d-row (128/4)
#define BH      128         // 8*16 batch*heads
#define BH_PER_THREAD 16
#define GROUPS  (BH / BH_PER_THREAD)   // 8

__global__ __launch_bounds__(256)
void rope_kernel(const float* __restrict__ x,
                 const int*   __restrict__ pos,
                 float*       __restrict__ out) {
    const int tid = blockIdx.x * 256 + threadIdx.x;     // 0 .. 1048575
    const int idx = tid & (S_LEN * CHUNKS - 1);          // 0 .. 131071
    const int g   = tid >> 17;                           // bh group 0..7

    const int s = idx >> 5;          // sequence position 0..4095
    const int c = idx & 31;          // float4 chunk -> pairs k=2c, 2c+1

    const float p = (float)pos[s];

    // inv_freq[k] = 10000^(-2k/128)
    const float lg = (-2.0f / 128.0f) * logf(10000.0f);
    const float f0 = __expf(lg * (float)(2 * c));
    const float f1 = __expf(lg * (float)(2 * c + 1));

    float s0, c0, s1, c1;
    sincosf(p * f0, &s0, &c0);
    sincosf(p * f1, &s1, &c1);

    const size_t stride = (size_t)S_LEN * D_HEAD;        // one bh-slice
    size_t base = (size_t)(g * BH_PER_THREAD) * stride
                + (size_t)s * D_HEAD + (size_t)(c * 4);

    #pragma unroll 8
    for (int i = 0; i < BH_PER_THREAD; ++i) {
        const f32x4 v = __builtin_nontemporal_load(
            reinterpret_cast<const f32x4*>(x + base));
        f32x4 o;
        o.x = c0 * v.x - s0 * v.y;
        o.y = s0 * v.x + c0 * v.y;
        o.z = c1 * v.z - s1 * v.w;
        o.w = s1 * v.z + c1 * v.w;
        __builtin_nontemporal_store(o, reinterpret_cast<f32x4*>(out + base));
        base += stride;
    }
}

extern "C" void kernel_launch(void* const* d_in, const int* in_sizes, int n_in,
                              void* d_out, int out_size, void* d_ws, size_t ws_size,
                              hipStream_t stream) {
    const float* x   = (const float*)d_in[0];
    const int*   pos = (const int*)d_in[1];
    float*       out = (float*)d_out;

    const int total  = GROUPS * S_LEN * CHUNKS;   // 1,048,576 threads
    const int blocks = total / 256;               // 4096
    rope_kernel<<<blocks, 256, 0, stream>>>(x, pos, out);
}

// Round 4
// 85.076 us; speedup vs baseline: 1.2672x; 1.0822x over previous
//
#include <hip/hip_runtime.h>
#include <math.h>

// RoPE: x (8,16,4096,128) fp32, interleaved even/odd pairing.
// out[..., 2k]   = cos(ang_k)*x[...,2k] - sin(ang_k)*x[...,2k+1]
// out[..., 2k+1] = sin(ang_k)*x[...,2k] + cos(ang_k)*x[...,2k+1]
// ang_k = pos * 10000^(-2k/128)
//
// Memory-bound streaming kernel (537 MB traffic, zero reuse, working set
// 2x the 256 MiB L3).
//  - one thread owns one (s, float4-chunk) angle pair -> sincos amortized
//    over 16 bh-slices; hot loop is NT-load -> 8 FMA -> store.
//  - ASYMMETRIC cache policy: NT loads (read stream has zero reuse,
//    would thrash L2/L3), REGULAR stores (full-line coalesced writes
//    write-combine in L2 — the 7.0 TB/s memset path — no write-allocate
//    fetch since each wave writes whole 128B lines).
//  - unroll 8: 8 loads in flight per wave.

typedef float f32x4 __attribute__((ext_vector_type(4)));

#define S_LEN   4096
#define D_HEAD  128
#define CHUNKS  32          // float4 chunks per d-row (128/4)
#define BH      128         // 8*16 batch*heads
#define BH_PER_THREAD 16
#define GROUPS  (BH / BH_PER_THREAD)   // 8

__global__ __launch_bounds__(256)
void rope_kernel(const float* __restrict__ x,
                 const int*   __restrict__ pos,
                 float*       __restrict__ out) {
    const int tid = blockIdx.x * 256 + threadIdx.x;     // 0 .. 1048575
    const int idx = tid & (S_LEN * CHUNKS - 1);          // 0 .. 131071
    const int g   = tid >> 17;                           // bh group 0..7

    const int s = idx >> 5;          // sequence position 0..4095
    const int c = idx & 31;          // float4 chunk -> pairs k=2c, 2c+1

    const float p = (float)pos[s];

    // inv_freq[k] = 10000^(-2k/128)
    const float lg = (-2.0f / 128.0f) * logf(10000.0f);
    const float f0 = __expf(lg * (float)(2 * c));
    const float f1 = __expf(lg * (float)(2 * c + 1));

    float s0, c0, s1, c1;
    sincosf(p * f0, &s0, &c0);
    sincosf(p * f1, &s1, &c1);

    const size_t stride = (size_t)S_LEN * D_HEAD;        // one bh-slice
    size_t base = (size_t)(g * BH_PER_THREAD) * stride
                + (size_t)s * D_HEAD + (size_t)(c * 4);

    #pragma unroll 8
    for (int i = 0; i < BH_PER_THREAD; ++i) {
        const f32x4 v = __builtin_nontemporal_load(
            reinterpret_cast<const f32x4*>(x + base));
        f32x4 o;
        o.x = c0 * v.x - s0 * v.y;
        o.y = s0 * v.x + c0 * v.y;
        o.z = c1 * v.z - s1 * v.w;
        o.w = s1 * v.z + c1 * v.w;
        *reinterpret_cast<f32x4*>(out + base) = o;   // regular (cached) store
        base += stride;
    }
}

extern "C" void kernel_launch(void* const* d_in, const int* in_sizes, int n_in,
                              void* d_out, int out_size, void* d_ws, size_t ws_size,
                              hipStream_t stream) {
    const float* x   = (const float*)d_in[0];
    const int*   pos = (const int*)d_in[1];
    float*       out = (float*)d_out;

    const int total  = GROUPS * S_LEN * CHUNKS;   // 1,048,576 threads
    const int blocks = total / 256;               // 4096
    rope_kernel<<<blocks, 256, 0, stream>>>(x, pos, out);
}